// Round 1
// baseline (1243.209 us; speedup 1.0000x reference)
//
#include <hip/hip_runtime.h>

#define N_NODES 100000
#define N_EDGES 1600000
#define DIM 64

// One wave (64 lanes) per edge; lane = feature dim.
// Row gathers h_real[src]/h_imag[src] are 256B contiguous per wave -> coalesced.
// Scatter via global f32 atomics (device-scope by default, cross-XCD safe).
__global__ __launch_bounds__(256) void edge_scatter_kernel(
    const float* __restrict__ h_real, const float* __restrict__ h_imag,
    const float* __restrict__ dvec,
    const float* __restrict__ w_real, const float* __restrict__ w_imag,
    const int* __restrict__ src, const int* __restrict__ dst,
    float* __restrict__ z_real, float* __restrict__ z_imag) {
  const int lane = threadIdx.x & 63;
  const int e = blockIdx.x * (blockDim.x >> 6) + (threadIdx.x >> 6);
  if (e >= N_EDGES) return;

  const int s = src[e];
  const int t = dst[e];
  const float dd = dvec[t] * dvec[s];
  const float er = dd * w_real[e];
  const float ei = dd * w_imag[e];

  const float hr = h_real[(size_t)s * DIM + lane];
  const float hi = h_imag[(size_t)s * DIM + lane];

  atomicAdd(&z_real[(size_t)t * DIM + lane], er * hr - ei * hi);
  atomicAdd(&z_imag[(size_t)t * DIM + lane], ei * hr + er * hi);
}

// One wave per node, lane = output feature j.
// W1/W2 staged transposed in LDS: lanes read Wt[k*64 + lane] -> consecutive
// addresses, 2 lanes/bank (free). z-row reads are same-address broadcasts.
__global__ __launch_bounds__(256) void epilogue_kernel(
    const float* __restrict__ z_real, const float* __restrict__ z_imag,
    const float* __restrict__ W1, const float* __restrict__ b1,
    const float* __restrict__ W2, const float* __restrict__ b2,
    float* __restrict__ zr_out, float* __restrict__ zi_out) {
  __shared__ float W1t[DIM * DIM];
  __shared__ float W2t[DIM * DIM];
  __shared__ float b1s[DIM], b2s[DIM];
  __shared__ float zr_row[4][DIM], zi_row[4][DIM], zrn_row[4][DIM];

  for (int idx = threadIdx.x; idx < DIM * DIM; idx += blockDim.x) {
    const int j = idx >> 6, k = idx & 63;
    W1t[k * DIM + j] = W1[idx];
    W2t[k * DIM + j] = W2[idx];
  }
  if (threadIdx.x < DIM) {
    b1s[threadIdx.x] = b1[threadIdx.x];
    b2s[threadIdx.x] = b2[threadIdx.x];
  }

  const int wave = threadIdx.x >> 6;
  const int lane = threadIdx.x & 63;
  const int n = blockIdx.x * 4 + wave;  // N_NODES % 4 == 0, grid = N/4 exact

  zr_row[wave][lane] = z_real[(size_t)n * DIM + lane];
  zi_row[wave][lane] = z_imag[(size_t)n * DIM + lane];
  __syncthreads();

  // zr = z_real @ W1^T + b1 - (z_imag @ W2^T + b2)
  float accr = b1s[lane] - b2s[lane];
#pragma unroll 8
  for (int k = 0; k < DIM; ++k) {
    accr += zr_row[wave][k] * W1t[k * DIM + lane]
          - zi_row[wave][k] * W2t[k * DIM + lane];
  }
  zrn_row[wave][lane] = accr;
  __syncthreads();

  // zi = zr_new @ W2^T + b2 + (z_imag @ W1^T + b1)
  float acci = b1s[lane] + b2s[lane];
#pragma unroll 8
  for (int k = 0; k < DIM; ++k) {
    acci += zrn_row[wave][k] * W2t[k * DIM + lane]
          + zi_row[wave][k] * W1t[k * DIM + lane];
  }

  zr_out[(size_t)n * DIM + lane] = accr;
  zi_out[(size_t)n * DIM + lane] = acci;
}

extern "C" void kernel_launch(void* const* d_in, const int* in_sizes, int n_in,
                              void* d_out, int out_size, void* d_ws, size_t ws_size,
                              hipStream_t stream) {
  const float* h_real = (const float*)d_in[0];
  const float* h_imag = (const float*)d_in[1];
  const float* dvec   = (const float*)d_in[2];
  const float* w_real = (const float*)d_in[3];
  const float* w_imag = (const float*)d_in[4];
  const int*   src    = (const int*)d_in[5];
  const int*   dst    = (const int*)d_in[6];
  const float* W1     = (const float*)d_in[7];
  const float* b1     = (const float*)d_in[8];
  const float* W2     = (const float*)d_in[9];
  const float* b2     = (const float*)d_in[10];

  float* z_real = (float*)d_ws;
  float* z_imag = z_real + (size_t)N_NODES * DIM;
  hipMemsetAsync(d_ws, 0, (size_t)2 * N_NODES * DIM * sizeof(float), stream);

  float* zr_out = (float*)d_out;
  float* zi_out = zr_out + (size_t)N_NODES * DIM;

  const int edges_per_block = 256 / 64;
  edge_scatter_kernel<<<(N_EDGES + edges_per_block - 1) / edges_per_block, 256, 0,
                        stream>>>(h_real, h_imag, dvec, w_real, w_imag, src, dst,
                                  z_real, z_imag);

  epilogue_kernel<<<N_NODES / 4, 256, 0, stream>>>(z_real, z_imag, W1, b1, W2, b2,
                                                   zr_out, zi_out);
}

// Round 2
// 575.672 us; speedup vs baseline: 2.1596x; 2.1596x over previous
//
#include <hip/hip_runtime.h>

#define N_NODES 100000
#define N_EDGES 1600000
#define DIM 64

#define SCAN_BLOCK 1024
#define N_SCAN_BLOCKS ((N_NODES + SCAN_BLOCK - 1) / SCAN_BLOCK)  // 98

// ---------------- ws layout ----------------
// records : E * 16 B   (float4 {src_bits, d_src*wr, d_src*wi, pad})
// inc     : N ints     (inclusive prefix of degree histogram)
// cnt     : N ints
// cursor  : N ints
// bsum    : N_SCAN_BLOCKS ints
// bpre    : N_SCAN_BLOCKS ints
// total ~26.9 MB

__device__ __forceinline__ float bcast(float x, int k) {
  return __int_as_float(__builtin_amdgcn_readlane(__float_as_int(x), k));
}

__global__ __launch_bounds__(256) void hist_kernel(const int* __restrict__ dst,
                                                   int* __restrict__ cnt) {
  int e = blockIdx.x * blockDim.x + threadIdx.x;
  if (e < N_EDGES) atomicAdd(&cnt[dst[e]], 1);
}

__global__ __launch_bounds__(SCAN_BLOCK) void scan1_kernel(
    const int* __restrict__ cnt, int* __restrict__ inc, int* __restrict__ bsum) {
  __shared__ int s[SCAN_BLOCK];
  const int tid = threadIdx.x;
  const int i = blockIdx.x * SCAN_BLOCK + tid;
  s[tid] = (i < N_NODES) ? cnt[i] : 0;
  __syncthreads();
#pragma unroll
  for (int off = 1; off < SCAN_BLOCK; off <<= 1) {
    int t = (tid >= off) ? s[tid - off] : 0;
    __syncthreads();
    s[tid] += t;
    __syncthreads();
  }
  if (i < N_NODES) inc[i] = s[tid];
  if (tid == SCAN_BLOCK - 1) bsum[blockIdx.x] = s[tid];
}

__global__ void scan2_kernel(const int* __restrict__ bsum, int* __restrict__ bpre) {
  if (threadIdx.x == 0 && blockIdx.x == 0) {
    int run = 0;
    for (int b = 0; b < N_SCAN_BLOCKS; ++b) {
      bpre[b] = run;
      run += bsum[b];
    }
  }
}

__global__ __launch_bounds__(SCAN_BLOCK) void scan3_kernel(
    const int* __restrict__ cnt, int* __restrict__ inc,
    const int* __restrict__ bpre, int* __restrict__ cursor) {
  const int i = blockIdx.x * SCAN_BLOCK + threadIdx.x;
  if (i < N_NODES) {
    int v = inc[i] + bpre[blockIdx.x];
    inc[i] = v;                 // global inclusive prefix
    cursor[i] = v - cnt[i];     // exclusive prefix = write cursor
  }
}

__global__ __launch_bounds__(256) void scatter_records_kernel(
    const int* __restrict__ src, const int* __restrict__ dst,
    const float* __restrict__ dvec,
    const float* __restrict__ w_real, const float* __restrict__ w_imag,
    int* __restrict__ cursor, float4* __restrict__ records) {
  int e = blockIdx.x * blockDim.x + threadIdx.x;
  if (e >= N_EDGES) return;
  const int t = dst[e];
  const int s = src[e];
  const float ds = dvec[s];
  const int pos = atomicAdd(&cursor[t], 1);
  float4 rec;
  rec.x = __int_as_float(s);
  rec.y = ds * w_real[e];
  rec.z = ds * w_imag[e];
  rec.w = 0.0f;
  records[pos] = rec;
}

// One wave per node: accumulate z-row in registers, single coalesced write.
__global__ __launch_bounds__(256) void pull_kernel(
    const float4* __restrict__ records, const int* __restrict__ inc,
    const float* __restrict__ dvec,
    const float* __restrict__ h_real, const float* __restrict__ h_imag,
    float* __restrict__ z_real, float* __restrict__ z_imag) {
  const int lane = threadIdx.x & 63;
  const int n = blockIdx.x * (blockDim.x >> 6) + (threadIdx.x >> 6);
  if (n >= N_NODES) return;

  const int start = (n == 0) ? 0 : inc[n - 1];
  const int end = inc[n];
  const float dn = dvec[n];

  float accr = 0.0f, acci = 0.0f;
  for (int p = start; p < end; ++p) {
    const float4 rec = records[p];  // wave-uniform address (broadcast)
    const int s = __float_as_int(rec.x);
    const float er = dn * rec.y;
    const float ei = dn * rec.z;
    const float hr = h_real[(size_t)s * DIM + lane];
    const float hi = h_imag[(size_t)s * DIM + lane];
    accr += er * hr - ei * hi;
    acci += ei * hr + er * hi;
  }
  z_real[(size_t)n * DIM + lane] = accr;
  z_imag[(size_t)n * DIM + lane] = acci;
}

// In-place epilogue on d_out. Lane j holds W1/W2 row j in registers (128 VGPR);
// z elements broadcast via v_readlane in fully-unrolled loops. Grid-stride so
// the one-time W load is amortized over ~60 nodes per wave.
__global__ __launch_bounds__(256) void epilogue_kernel(
    float* __restrict__ z_real, float* __restrict__ z_imag,
    const float* __restrict__ W1, const float* __restrict__ b1,
    const float* __restrict__ W2, const float* __restrict__ b2) {
  const int lane = threadIdx.x & 63;

  float w1r[DIM], w2r[DIM];
#pragma unroll
  for (int q = 0; q < DIM / 4; ++q) {
    const float4 v1 = reinterpret_cast<const float4*>(W1)[lane * (DIM / 4) + q];
    const float4 v2 = reinterpret_cast<const float4*>(W2)[lane * (DIM / 4) + q];
    w1r[4 * q + 0] = v1.x; w1r[4 * q + 1] = v1.y;
    w1r[4 * q + 2] = v1.z; w1r[4 * q + 3] = v1.w;
    w2r[4 * q + 0] = v2.x; w2r[4 * q + 1] = v2.y;
    w2r[4 * q + 2] = v2.z; w2r[4 * q + 3] = v2.w;
  }
  const float b1l = b1[lane];
  const float b2l = b2[lane];

  const int wave_id = blockIdx.x * (blockDim.x >> 6) + (threadIdx.x >> 6);
  const int n_waves = gridDim.x * (blockDim.x >> 6);

  for (int n = wave_id; n < N_NODES; n += n_waves) {
    const float zr_in = z_real[(size_t)n * DIM + lane];
    const float zi_in = z_imag[(size_t)n * DIM + lane];

    // zr = z_real @ W1^T + b1 - (z_imag @ W2^T + b2)
    float accr = b1l - b2l;
#pragma unroll
    for (int k = 0; k < DIM; ++k) {
      accr += bcast(zr_in, k) * w1r[k] - bcast(zi_in, k) * w2r[k];
    }
    // zi = zr_new @ W2^T + b2 + (z_imag @ W1^T + b1)
    float acci = b1l + b2l;
#pragma unroll
    for (int k = 0; k < DIM; ++k) {
      acci += bcast(accr, k) * w2r[k] + bcast(zi_in, k) * w1r[k];
    }
    z_real[(size_t)n * DIM + lane] = accr;
    z_imag[(size_t)n * DIM + lane] = acci;
  }
}

extern "C" void kernel_launch(void* const* d_in, const int* in_sizes, int n_in,
                              void* d_out, int out_size, void* d_ws, size_t ws_size,
                              hipStream_t stream) {
  const float* h_real = (const float*)d_in[0];
  const float* h_imag = (const float*)d_in[1];
  const float* dvec   = (const float*)d_in[2];
  const float* w_real = (const float*)d_in[3];
  const float* w_imag = (const float*)d_in[4];
  const int*   src    = (const int*)d_in[5];
  const int*   dst    = (const int*)d_in[6];
  const float* W1     = (const float*)d_in[7];
  const float* b1     = (const float*)d_in[8];
  const float* W2     = (const float*)d_in[9];
  const float* b2     = (const float*)d_in[10];

  char* ws = (char*)d_ws;
  float4* records = (float4*)ws;                       // 25.6 MB
  int* inc    = (int*)(ws + (size_t)N_EDGES * 16);     // 400 KB
  int* cnt    = inc + N_NODES;
  int* cursor = cnt + N_NODES;
  int* bsum   = cursor + N_NODES;
  int* bpre   = bsum + N_SCAN_BLOCKS;

  hipMemsetAsync(cnt, 0, (size_t)N_NODES * sizeof(int), stream);

  float* z_real = (float*)d_out;
  float* z_imag = z_real + (size_t)N_NODES * DIM;

  hist_kernel<<<(N_EDGES + 255) / 256, 256, 0, stream>>>(dst, cnt);
  scan1_kernel<<<N_SCAN_BLOCKS, SCAN_BLOCK, 0, stream>>>(cnt, inc, bsum);
  scan2_kernel<<<1, 64, 0, stream>>>(bsum, bpre);
  scan3_kernel<<<N_SCAN_BLOCKS, SCAN_BLOCK, 0, stream>>>(cnt, inc, bpre, cursor);
  scatter_records_kernel<<<(N_EDGES + 255) / 256, 256, 0, stream>>>(
      src, dst, dvec, w_real, w_imag, cursor, records);

  const int waves_per_block = 4;
  pull_kernel<<<(N_NODES + waves_per_block - 1) / waves_per_block, 256, 0,
                stream>>>(records, inc, dvec, h_real, h_imag, z_real, z_imag);

  epilogue_kernel<<<512, 256, 0, stream>>>(z_real, z_imag, W1, b1, W2, b2);
}

// Round 3
// 479.056 us; speedup vs baseline: 2.5951x; 1.2017x over previous
//
#include <hip/hip_runtime.h>
#include <hip/hip_bf16.h>

#define N_NODES 100000
#define N_EDGES 1600000
#define DIM 64

#define SCAN_BLOCK 1024
#define N_SCAN_BLOCKS ((N_NODES + SCAN_BLOCK - 1) / SCAN_BLOCK)  // 98

// ---------------- ws layout ----------------
// records : E * 8 B    (uint2 {src, bf16x2(d_src*wr, d_src*wi)})
// hpack   : N*DIM * 4B (uint {bf16(hr) lo, bf16(hi) hi})
// inc     : N ints
// cnt     : N ints
// cursor  : N ints
// bsum/bpre : N_SCAN_BLOCKS ints each
// total ~38.9 MB

__device__ __forceinline__ float bcast(float x, int k) {
  return __int_as_float(__builtin_amdgcn_readlane(__float_as_int(x), k));
}

__device__ __forceinline__ unsigned pack_bf16x2(float lo, float hi) {
  unsigned ulo = (unsigned)__hip_bfloat16_raw(__float2bfloat16(lo)).x;
  unsigned uhi = (unsigned)__hip_bfloat16_raw(__float2bfloat16(hi)).x;
  return ulo | (uhi << 16);
}

__device__ __forceinline__ float unpack_lo(unsigned u) {
  return __int_as_float((int)(u << 16));
}
__device__ __forceinline__ float unpack_hi(unsigned u) {
  return __int_as_float((int)(u & 0xFFFF0000u));
}

// Pack h_real/h_imag into interleaved bf16x2: one 4B gather per feature in pull.
__global__ __launch_bounds__(256) void pack_h_kernel(
    const float* __restrict__ h_real, const float* __restrict__ h_imag,
    unsigned* __restrict__ hpack) {
  int i = blockIdx.x * blockDim.x + threadIdx.x;
  if (i < N_NODES * DIM) hpack[i] = pack_bf16x2(h_real[i], h_imag[i]);
}

__global__ __launch_bounds__(256) void hist_kernel(const int* __restrict__ dst,
                                                   int* __restrict__ cnt) {
  int e = blockIdx.x * blockDim.x + threadIdx.x;
  if (e < N_EDGES) atomicAdd(&cnt[dst[e]], 1);
}

__global__ __launch_bounds__(SCAN_BLOCK) void scan1_kernel(
    const int* __restrict__ cnt, int* __restrict__ inc, int* __restrict__ bsum) {
  __shared__ int s[SCAN_BLOCK];
  const int tid = threadIdx.x;
  const int i = blockIdx.x * SCAN_BLOCK + tid;
  s[tid] = (i < N_NODES) ? cnt[i] : 0;
  __syncthreads();
#pragma unroll
  for (int off = 1; off < SCAN_BLOCK; off <<= 1) {
    int t = (tid >= off) ? s[tid - off] : 0;
    __syncthreads();
    s[tid] += t;
    __syncthreads();
  }
  if (i < N_NODES) inc[i] = s[tid];
  if (tid == SCAN_BLOCK - 1) bsum[blockIdx.x] = s[tid];
}

__global__ void scan2_kernel(const int* __restrict__ bsum, int* __restrict__ bpre) {
  if (threadIdx.x == 0 && blockIdx.x == 0) {
    int run = 0;
    for (int b = 0; b < N_SCAN_BLOCKS; ++b) {
      bpre[b] = run;
      run += bsum[b];
    }
  }
}

__global__ __launch_bounds__(SCAN_BLOCK) void scan3_kernel(
    const int* __restrict__ cnt, int* __restrict__ inc,
    const int* __restrict__ bpre, int* __restrict__ cursor) {
  const int i = blockIdx.x * SCAN_BLOCK + threadIdx.x;
  if (i < N_NODES) {
    int v = inc[i] + bpre[blockIdx.x];
    inc[i] = v;
    cursor[i] = v - cnt[i];
  }
}

__global__ __launch_bounds__(256) void scatter_records_kernel(
    const int* __restrict__ src, const int* __restrict__ dst,
    const float* __restrict__ dvec,
    const float* __restrict__ w_real, const float* __restrict__ w_imag,
    int* __restrict__ cursor, uint2* __restrict__ records) {
  int e = blockIdx.x * blockDim.x + threadIdx.x;
  if (e >= N_EDGES) return;
  const int t = dst[e];
  const int s = src[e];
  const float ds = dvec[s];
  const int pos = atomicAdd(&cursor[t], 1);
  uint2 rec;
  rec.x = (unsigned)s;
  rec.y = pack_bf16x2(ds * w_real[e], ds * w_imag[e]);
  records[pos] = rec;
}

// One wave per node; unrolled x4 for memory-level parallelism.
__global__ __launch_bounds__(256) void pull_kernel(
    const uint2* __restrict__ records, const int* __restrict__ inc,
    const float* __restrict__ dvec, const unsigned* __restrict__ hpack,
    float* __restrict__ z_real, float* __restrict__ z_imag) {
  const int lane = threadIdx.x & 63;
  const int n = blockIdx.x * (blockDim.x >> 6) + (threadIdx.x >> 6);
  if (n >= N_NODES) return;

  const int start = (n == 0) ? 0 : inc[n - 1];
  const int end = inc[n];
  const unsigned* __restrict__ hl = hpack + lane;

  float sr = 0.0f, si = 0.0f;
  int p = start;
  for (; p + 4 <= end; p += 4) {
    const uint2 r0 = records[p + 0];
    const uint2 r1 = records[p + 1];
    const uint2 r2 = records[p + 2];
    const uint2 r3 = records[p + 3];
    const unsigned h0 = hl[(size_t)r0.x * DIM];
    const unsigned h1 = hl[(size_t)r1.x * DIM];
    const unsigned h2 = hl[(size_t)r2.x * DIM];
    const unsigned h3 = hl[(size_t)r3.x * DIM];
#define ACC(RR, HH)                                                  \
    {                                                                \
      const float er = unpack_lo(RR.y), ei = unpack_hi(RR.y);        \
      const float hr = unpack_lo(HH), hi = unpack_hi(HH);            \
      sr += er * hr - ei * hi;                                       \
      si += ei * hr + er * hi;                                       \
    }
    ACC(r0, h0) ACC(r1, h1) ACC(r2, h2) ACC(r3, h3)
  }
  for (; p < end; ++p) {
    const uint2 r0 = records[p];
    const unsigned h0 = hl[(size_t)r0.x * DIM];
    ACC(r0, h0)
  }
#undef ACC

  const float dn = dvec[n];
  z_real[(size_t)n * DIM + lane] = dn * sr;
  z_imag[(size_t)n * DIM + lane] = dn * si;
}

// In-place epilogue on d_out: lane j holds W1/W2 row j (128 VGPR), z broadcast
// via readlane; grid-stride amortizes the W load over ~49 nodes per wave.
__global__ __launch_bounds__(256) void epilogue_kernel(
    float* __restrict__ z_real, float* __restrict__ z_imag,
    const float* __restrict__ W1, const float* __restrict__ b1,
    const float* __restrict__ W2, const float* __restrict__ b2) {
  const int lane = threadIdx.x & 63;

  float w1r[DIM], w2r[DIM];
#pragma unroll
  for (int q = 0; q < DIM / 4; ++q) {
    const float4 v1 = reinterpret_cast<const float4*>(W1)[lane * (DIM / 4) + q];
    const float4 v2 = reinterpret_cast<const float4*>(W2)[lane * (DIM / 4) + q];
    w1r[4 * q + 0] = v1.x; w1r[4 * q + 1] = v1.y;
    w1r[4 * q + 2] = v1.z; w1r[4 * q + 3] = v1.w;
    w2r[4 * q + 0] = v2.x; w2r[4 * q + 1] = v2.y;
    w2r[4 * q + 2] = v2.z; w2r[4 * q + 3] = v2.w;
  }
  const float b1l = b1[lane];
  const float b2l = b2[lane];

  const int wave_id = blockIdx.x * (blockDim.x >> 6) + (threadIdx.x >> 6);
  const int n_waves = gridDim.x * (blockDim.x >> 6);

  for (int n = wave_id; n < N_NODES; n += n_waves) {
    const float zr_in = z_real[(size_t)n * DIM + lane];
    const float zi_in = z_imag[(size_t)n * DIM + lane];

    float accr = b1l - b2l;
#pragma unroll
    for (int k = 0; k < DIM; ++k) {
      accr += bcast(zr_in, k) * w1r[k] - bcast(zi_in, k) * w2r[k];
    }
    float acci = b1l + b2l;
#pragma unroll
    for (int k = 0; k < DIM; ++k) {
      acci += bcast(accr, k) * w2r[k] + bcast(zi_in, k) * w1r[k];
    }
    z_real[(size_t)n * DIM + lane] = accr;
    z_imag[(size_t)n * DIM + lane] = acci;
  }
}

extern "C" void kernel_launch(void* const* d_in, const int* in_sizes, int n_in,
                              void* d_out, int out_size, void* d_ws, size_t ws_size,
                              hipStream_t stream) {
  const float* h_real = (const float*)d_in[0];
  const float* h_imag = (const float*)d_in[1];
  const float* dvec   = (const float*)d_in[2];
  const float* w_real = (const float*)d_in[3];
  const float* w_imag = (const float*)d_in[4];
  const int*   src    = (const int*)d_in[5];
  const int*   dst    = (const int*)d_in[6];
  const float* W1     = (const float*)d_in[7];
  const float* b1     = (const float*)d_in[8];
  const float* W2     = (const float*)d_in[9];
  const float* b2     = (const float*)d_in[10];

  char* ws = (char*)d_ws;
  uint2* records = (uint2*)ws;                                  // 12.8 MB
  unsigned* hpack = (unsigned*)(ws + (size_t)N_EDGES * 8);      // 25.6 MB
  int* inc    = (int*)(ws + (size_t)N_EDGES * 8 + (size_t)N_NODES * DIM * 4);
  int* cnt    = inc + N_NODES;
  int* cursor = cnt + N_NODES;
  int* bsum   = cursor + N_NODES;
  int* bpre   = bsum + N_SCAN_BLOCKS;

  hipMemsetAsync(cnt, 0, (size_t)N_NODES * sizeof(int), stream);

  float* z_real = (float*)d_out;
  float* z_imag = z_real + (size_t)N_NODES * DIM;

  pack_h_kernel<<<(N_NODES * DIM + 255) / 256, 256, 0, stream>>>(h_real, h_imag,
                                                                 hpack);
  hist_kernel<<<(N_EDGES + 255) / 256, 256, 0, stream>>>(dst, cnt);
  scan1_kernel<<<N_SCAN_BLOCKS, SCAN_BLOCK, 0, stream>>>(cnt, inc, bsum);
  scan2_kernel<<<1, 64, 0, stream>>>(bsum, bpre);
  scan3_kernel<<<N_SCAN_BLOCKS, SCAN_BLOCK, 0, stream>>>(cnt, inc, bpre, cursor);
  scatter_records_kernel<<<(N_EDGES + 255) / 256, 256, 0, stream>>>(
      src, dst, dvec, w_real, w_imag, cursor, records);

  const int waves_per_block = 4;
  pull_kernel<<<(N_NODES + waves_per_block - 1) / waves_per_block, 256, 0,
                stream>>>(records, inc, dvec, hpack, z_real, z_imag);

  epilogue_kernel<<<512, 256, 0, stream>>>(z_real, z_imag, W1, b1, W2, b2);
}

// Round 4
// 402.801 us; speedup vs baseline: 3.0864x; 1.1893x over previous
//
#include <hip/hip_runtime.h>
#include <hip/hip_bf16.h>

#define N_NODES 100000
#define N_EDGES 1600000
#define DIM 64

#define SCAN_BLOCK 1024
#define N_SCAN_BLOCKS ((N_NODES + SCAN_BLOCK - 1) / SCAN_BLOCK)  // 98

typedef __attribute__((ext_vector_type(8))) short bf16x8;
typedef __attribute__((ext_vector_type(4))) float f32x4;

// ---------------- ws layout ----------------
// At      : 128*128*2 B bf16 (combined epilogue matrix, transposed: At[n][k])
// cvec    : 256 * 4 B  (combined bias, first 128 used)
// records : E * 8 B    (uint2 {src, bf16x2(d_src*wr, d_src*wi)})
// hpack   : N*DIM * 4B (uint {bf16(hr) lo, bf16(hi) hi})
// inc/cnt/cursor : N ints each; bsum/bpre : N_SCAN_BLOCKS ints
// total ~38.5 MB
//
// Zcat ([N][128] bf16 = 25.6 MB) lives in the zi half of d_out: zcat row n
// occupies exactly the bytes of zi_out row n; the epilogue wave loads all its
// A fragments (16 zcat rows) into registers before storing those same rows.

__device__ __forceinline__ unsigned pack_bf16x2(float lo, float hi) {
  unsigned ulo = (unsigned)__hip_bfloat16_raw(__float2bfloat16(lo)).x;
  unsigned uhi = (unsigned)__hip_bfloat16_raw(__float2bfloat16(hi)).x;
  return ulo | (uhi << 16);
}
__device__ __forceinline__ float unpack_lo(unsigned u) {
  return __int_as_float((int)(u << 16));
}
__device__ __forceinline__ float unpack_hi(unsigned u) {
  return __int_as_float((int)(u & 0xFFFF0000u));
}
__device__ __forceinline__ unsigned short f2bf(float x) {
  return __hip_bfloat16_raw(__float2bfloat16(x)).x;
}

// Build combined epilogue operator:
// zr = zr_in@W1^T - zi_in@W2^T + (b1-b2)
// zi = zr_in@(W1^T W2^T) + zi_in@(W1^T - W2^T W2^T) + ((b1-b2)@W2^T + b1 + b2)
// At[n][k] (bf16) = A_comb[k][n], n=output feature (0..63 zr, 64..127 zi),
// k = input feature (0..63 zr_in, 64..127 zi_in). cvec[n] = combined bias.
__global__ __launch_bounds__(256) void precompute_kernel(
    const float* __restrict__ W1, const float* __restrict__ b1,
    const float* __restrict__ W2, const float* __restrict__ b2,
    unsigned short* __restrict__ At, float* __restrict__ cvec) {
  const int idx = blockIdx.x * blockDim.x + threadIdx.x;
  if (idx < 128 * 128) {
    const int n = idx >> 7, k = idx & 127;
    float v;
    if (n < 64) {
      v = (k < 64) ? W1[n * 64 + k] : -W2[n * 64 + (k - 64)];
    } else {
      const int nn = n - 64;
      if (k < 64) {
        float s = 0.0f;
        for (int j = 0; j < 64; ++j) s += W1[j * 64 + k] * W2[nn * 64 + j];
        v = s;
      } else {
        const int kk = k - 64;
        float s = 0.0f;
        for (int j = 0; j < 64; ++j) s += W2[j * 64 + kk] * W2[nn * 64 + j];
        v = W1[nn * 64 + kk] - s;
      }
    }
    At[n * 128 + k] = f2bf(v);
  }
  if (idx < 128) {
    if (idx < 64) {
      cvec[idx] = b1[idx] - b2[idx];
    } else {
      const int nn = idx - 64;
      float s = 0.0f;
      for (int j = 0; j < 64; ++j) s += (b1[j] - b2[j]) * W2[nn * 64 + j];
      cvec[idx] = s + b1[nn] + b2[nn];
    }
  }
}

__global__ __launch_bounds__(256) void pack_h_kernel(
    const float* __restrict__ h_real, const float* __restrict__ h_imag,
    unsigned* __restrict__ hpack) {
  int i = blockIdx.x * blockDim.x + threadIdx.x;
  if (i < N_NODES * DIM) hpack[i] = pack_bf16x2(h_real[i], h_imag[i]);
}

__global__ __launch_bounds__(256) void hist_kernel(const int* __restrict__ dst,
                                                   int* __restrict__ cnt) {
  int e = blockIdx.x * blockDim.x + threadIdx.x;
  if (e < N_EDGES) atomicAdd(&cnt[dst[e]], 1);
}

__global__ __launch_bounds__(SCAN_BLOCK) void scan1_kernel(
    const int* __restrict__ cnt, int* __restrict__ inc, int* __restrict__ bsum) {
  __shared__ int s[SCAN_BLOCK];
  const int tid = threadIdx.x;
  const int i = blockIdx.x * SCAN_BLOCK + tid;
  s[tid] = (i < N_NODES) ? cnt[i] : 0;
  __syncthreads();
#pragma unroll
  for (int off = 1; off < SCAN_BLOCK; off <<= 1) {
    int t = (tid >= off) ? s[tid - off] : 0;
    __syncthreads();
    s[tid] += t;
    __syncthreads();
  }
  if (i < N_NODES) inc[i] = s[tid];
  if (tid == SCAN_BLOCK - 1) bsum[blockIdx.x] = s[tid];
}

__global__ void scan2_kernel(const int* __restrict__ bsum, int* __restrict__ bpre) {
  if (threadIdx.x == 0 && blockIdx.x == 0) {
    int run = 0;
    for (int b = 0; b < N_SCAN_BLOCKS; ++b) {
      bpre[b] = run;
      run += bsum[b];
    }
  }
}

__global__ __launch_bounds__(SCAN_BLOCK) void scan3_kernel(
    const int* __restrict__ cnt, int* __restrict__ inc,
    const int* __restrict__ bpre, int* __restrict__ cursor) {
  const int i = blockIdx.x * SCAN_BLOCK + threadIdx.x;
  if (i < N_NODES) {
    int v = inc[i] + bpre[blockIdx.x];
    inc[i] = v;
    cursor[i] = v - cnt[i];
  }
}

__global__ __launch_bounds__(256) void scatter_records_kernel(
    const int* __restrict__ src, const int* __restrict__ dst,
    const float* __restrict__ dvec,
    const float* __restrict__ w_real, const float* __restrict__ w_imag,
    int* __restrict__ cursor, uint2* __restrict__ records) {
  int e = blockIdx.x * blockDim.x + threadIdx.x;
  if (e >= N_EDGES) return;
  const int t = dst[e];
  const int s = src[e];
  const float ds = dvec[s];
  const int pos = atomicAdd(&cursor[t], 1);
  uint2 rec;
  rec.x = (unsigned)s;
  rec.y = pack_bf16x2(ds * w_real[e], ds * w_imag[e]);
  records[pos] = rec;
}

// One wave per node; unrolled x4 for memory-level parallelism.
// Writes Zcat row (128 bf16: zr|zi) for the MFMA epilogue.
__global__ __launch_bounds__(256) void pull_kernel(
    const uint2* __restrict__ records, const int* __restrict__ inc,
    const float* __restrict__ dvec, const unsigned* __restrict__ hpack,
    unsigned short* __restrict__ zcat) {
  const int lane = threadIdx.x & 63;
  const int n = blockIdx.x * (blockDim.x >> 6) + (threadIdx.x >> 6);
  if (n >= N_NODES) return;

  const int start = (n == 0) ? 0 : inc[n - 1];
  const int end = inc[n];
  const unsigned* __restrict__ hl = hpack + lane;

  float sr = 0.0f, si = 0.0f;
  int p = start;
  for (; p + 4 <= end; p += 4) {
    const uint2 r0 = records[p + 0];
    const uint2 r1 = records[p + 1];
    const uint2 r2 = records[p + 2];
    const uint2 r3 = records[p + 3];
    const unsigned h0 = hl[(size_t)r0.x * DIM];
    const unsigned h1 = hl[(size_t)r1.x * DIM];
    const unsigned h2 = hl[(size_t)r2.x * DIM];
    const unsigned h3 = hl[(size_t)r3.x * DIM];
#define ACC(RR, HH)                                                  \
    {                                                                \
      const float er = unpack_lo(RR.y), ei = unpack_hi(RR.y);        \
      const float hr = unpack_lo(HH), hi = unpack_hi(HH);            \
      sr += er * hr - ei * hi;                                       \
      si += ei * hr + er * hi;                                       \
    }
    ACC(r0, h0) ACC(r1, h1) ACC(r2, h2) ACC(r3, h3)
  }
  for (; p < end; ++p) {
    const uint2 r0 = records[p];
    const unsigned h0 = hl[(size_t)r0.x * DIM];
    ACC(r0, h0)
  }
#undef ACC

  const float dn = dvec[n];
  zcat[(size_t)n * 128 + lane] = f2bf(dn * sr);
  zcat[(size_t)n * 128 + 64 + lane] = f2bf(dn * si);
}

// MFMA epilogue: Out[node][n] = sum_k Zcat[node][k] * A_comb[k][n] + cvec[n].
// One wave per 16-node tile; 8 n-tiles x 4 k-chunks of mfma_f32_16x16x32_bf16.
// NOTE: zcat aliases the zi half of d_out (per-node exact overlap). All A
// fragments are loaded into registers before any store; no __restrict__ on
// the aliasing pointers so the compiler preserves load->store order.
__global__ __launch_bounds__(256) void mfma_epilogue_kernel(
    const unsigned short* zcat, const unsigned short* __restrict__ At,
    const float* __restrict__ cvec, float* zr_out, float* zi_out) {
  const int lane = threadIdx.x & 63;
  const int tile = blockIdx.x * (blockDim.x >> 6) + (threadIdx.x >> 6);
  if (tile >= N_NODES / 16) return;
  const int node0 = tile * 16;
  const int m = lane & 15;   // A row (node) / B col (feature) / D col
  const int q = lane >> 4;   // k-group / D row group

  // A fragments: lane holds Zcat[node0+m][c*32 + q*8 .. +8]
  bf16x8 a[4];
  const unsigned short* arow = zcat + (size_t)(node0 + m) * 128 + q * 8;
#pragma unroll
  for (int c = 0; c < 4; ++c)
    a[c] = *reinterpret_cast<const bf16x8*>(arow + c * 32);

  f32x4 acc[8];
#pragma unroll
  for (int t = 0; t < 8; ++t) {
    acc[t] = (f32x4){0.f, 0.f, 0.f, 0.f};
    const unsigned short* brow = At + (size_t)(t * 16 + m) * 128 + q * 8;
#pragma unroll
    for (int c = 0; c < 4; ++c) {
      // B fragment: lane holds A_comb[c*32 + q*8 + j][t*16 + m] = At[t*16+m][...]
      bf16x8 b = *reinterpret_cast<const bf16x8*>(brow + c * 32);
      acc[t] = __builtin_amdgcn_mfma_f32_16x16x32_bf16(a[c], b, acc[t], 0, 0, 0);
    }
  }

  // C/D layout: col = lane&15, row = q*4 + reg
#pragma unroll
  for (int t = 0; t < 8; ++t) {
    const int n = t * 16 + m;
    const float bias = cvec[n];
    float* outp = (n < 64) ? zr_out : zi_out;
    const int nn = n & 63;
#pragma unroll
    for (int r = 0; r < 4; ++r) {
      const int node = node0 + q * 4 + r;
      outp[(size_t)node * 64 + nn] = acc[t][r] + bias;
    }
  }
}

extern "C" void kernel_launch(void* const* d_in, const int* in_sizes, int n_in,
                              void* d_out, int out_size, void* d_ws, size_t ws_size,
                              hipStream_t stream) {
  const float* h_real = (const float*)d_in[0];
  const float* h_imag = (const float*)d_in[1];
  const float* dvec   = (const float*)d_in[2];
  const float* w_real = (const float*)d_in[3];
  const float* w_imag = (const float*)d_in[4];
  const int*   src    = (const int*)d_in[5];
  const int*   dst    = (const int*)d_in[6];
  const float* W1     = (const float*)d_in[7];
  const float* b1     = (const float*)d_in[8];
  const float* W2     = (const float*)d_in[9];
  const float* b2     = (const float*)d_in[10];

  char* ws = (char*)d_ws;
  unsigned short* At = (unsigned short*)ws;                      // 32 KB
  float* cvec = (float*)(ws + 128 * 128 * 2);                    // 1 KB
  uint2* records = (uint2*)(ws + 33792);                         // 12.8 MB
  unsigned* hpack = (unsigned*)(ws + 33792 + (size_t)N_EDGES * 8);  // 25.6 MB
  int* inc = (int*)(ws + 33792 + (size_t)N_EDGES * 8 + (size_t)N_NODES * DIM * 4);
  int* cnt    = inc + N_NODES;
  int* cursor = cnt + N_NODES;
  int* bsum   = cursor + N_NODES;
  int* bpre   = bsum + N_SCAN_BLOCKS;

  hipMemsetAsync(cnt, 0, (size_t)N_NODES * sizeof(int), stream);

  float* zr_out = (float*)d_out;
  float* zi_out = zr_out + (size_t)N_NODES * DIM;
  // Zcat ([N][128] bf16) aliases the zi half of d_out byte-for-byte per node.
  unsigned short* zcat = (unsigned short*)zi_out;

  precompute_kernel<<<64, 256, 0, stream>>>(W1, b1, W2, b2, At, cvec);
  pack_h_kernel<<<(N_NODES * DIM + 255) / 256, 256, 0, stream>>>(h_real, h_imag,
                                                                 hpack);
  hist_kernel<<<(N_EDGES + 255) / 256, 256, 0, stream>>>(dst, cnt);
  scan1_kernel<<<N_SCAN_BLOCKS, SCAN_BLOCK, 0, stream>>>(cnt, inc, bsum);
  scan2_kernel<<<1, 64, 0, stream>>>(bsum, bpre);
  scan3_kernel<<<N_SCAN_BLOCKS, SCAN_BLOCK, 0, stream>>>(cnt, inc, bpre, cursor);
  scatter_records_kernel<<<(N_EDGES + 255) / 256, 256, 0, stream>>>(
      src, dst, dvec, w_real, w_imag, cursor, records);

  const int waves_per_block = 4;
  pull_kernel<<<(N_NODES + waves_per_block - 1) / waves_per_block, 256, 0,
                stream>>>(records, inc, dvec, hpack, zcat);

  const int tiles = N_NODES / 16;          // 6250
  mfma_epilogue_kernel<<<(tiles + 3) / 4, 256, 0, stream>>>(zcat, At, cvec,
                                                            zr_out, zi_out);
}

// Round 5
// 314.777 us; speedup vs baseline: 3.9495x; 1.2796x over previous
//
#include <hip/hip_runtime.h>
#include <hip/hip_bf16.h>

#define N_NODES 100000
#define N_EDGES 1600000
#define DIM 64

#define TILE 4096
#define B1 ((N_EDGES + TILE - 1) / TILE)       // 391 partition blocks
#define K1 98                                  // buckets of 1024 nodes
#define NCOUNTS (K1 * B1)                      // 38318
#define SCAN_BLOCK 1024
#define NSB_C ((NCOUNTS + SCAN_BLOCK - 1) / SCAN_BLOCK)  // 38

typedef __attribute__((ext_vector_type(8))) short bf16x8;
typedef __attribute__((ext_vector_type(4))) float f32x4;

// ---------------- ws layout ----------------
// At       : 32 KB bf16 (combined epilogue matrix, transposed)
// cvec     : 1 KB
// records1 : E * 8 B  bucket-grouped records (u64 {hi=wpair, lo=src|dl<<17})
// hpack    : N*DIM*4B ({bf16 hr, bf16 hi} interleaved)
// counts/cts_inc/coffs : NCOUNTS ints each; cbsum/cbpre : NSB_C ints
// inc      : N ints (global inclusive per-node prefix, written by place)
// total ~39.3 MB
//
// records_final (12.8 MB, node-grouped) lives in the zr half of d_out (dead
// until the epilogue overwrites it). Zcat (bf16 [N][128]) lives in the zi half.

__device__ __forceinline__ unsigned pack_bf16x2(float lo, float hi) {
  unsigned ulo = (unsigned)__hip_bfloat16_raw(__float2bfloat16(lo)).x;
  unsigned uhi = (unsigned)__hip_bfloat16_raw(__float2bfloat16(hi)).x;
  return ulo | (uhi << 16);
}
__device__ __forceinline__ float unpack_lo(unsigned u) {
  return __int_as_float((int)(u << 16));
}
__device__ __forceinline__ float unpack_hi(unsigned u) {
  return __int_as_float((int)(u & 0xFFFF0000u));
}
__device__ __forceinline__ unsigned short f2bf(float x) {
  return __hip_bfloat16_raw(__float2bfloat16(x)).x;
}

// Combined epilogue operator (see round-4 derivation):
// zr = zr_in@W1^T - zi_in@W2^T + (b1-b2)
// zi = zr_in@(W1^T W2^T) + zi_in@(W1^T - W2^T W2^T) + ((b1-b2)@W2^T + b1 + b2)
__global__ __launch_bounds__(256) void precompute_kernel(
    const float* __restrict__ W1, const float* __restrict__ b1,
    const float* __restrict__ W2, const float* __restrict__ b2,
    unsigned short* __restrict__ At, float* __restrict__ cvec) {
  const int idx = blockIdx.x * blockDim.x + threadIdx.x;
  if (idx < 128 * 128) {
    const int n = idx >> 7, k = idx & 127;
    float v;
    if (n < 64) {
      v = (k < 64) ? W1[n * 64 + k] : -W2[n * 64 + (k - 64)];
    } else {
      const int nn = n - 64;
      if (k < 64) {
        float s = 0.0f;
        for (int j = 0; j < 64; ++j) s += W1[j * 64 + k] * W2[nn * 64 + j];
        v = s;
      } else {
        const int kk = k - 64;
        float s = 0.0f;
        for (int j = 0; j < 64; ++j) s += W2[j * 64 + kk] * W2[nn * 64 + j];
        v = W1[nn * 64 + kk] - s;
      }
    }
    At[n * 128 + k] = f2bf(v);
  }
  if (idx < 128) {
    if (idx < 64) {
      cvec[idx] = b1[idx] - b2[idx];
    } else {
      const int nn = idx - 64;
      float s = 0.0f;
      for (int j = 0; j < 64; ++j) s += (b1[j] - b2[j]) * W2[nn * 64 + j];
      cvec[idx] = s + b1[nn] + b2[nn];
    }
  }
}

__global__ __launch_bounds__(256) void pack_h_kernel(
    const float* __restrict__ h_real, const float* __restrict__ h_imag,
    unsigned* __restrict__ hpack) {
  int i = blockIdx.x * blockDim.x + threadIdx.x;
  if (i < N_NODES * DIM) hpack[i] = pack_bf16x2(h_real[i], h_imag[i]);
}

// Per-(bucket, block) histogram; no global atomics (each cell single-writer).
__global__ __launch_bounds__(256) void hist_buckets_kernel(
    const int* __restrict__ dst, int* __restrict__ counts) {
  __shared__ int lh[K1];
  for (int i = threadIdx.x; i < K1; i += 256) lh[i] = 0;
  __syncthreads();
  const int e0 = blockIdx.x * TILE;
  const int e1 = min(e0 + TILE, N_EDGES);
  for (int e = e0 + threadIdx.x; e < e1; e += 256)
    atomicAdd(&lh[dst[e] >> 10], 1);
  __syncthreads();
  for (int b = threadIdx.x; b < K1; b += 256)
    counts[b * B1 + blockIdx.x] = lh[b];
}

__global__ __launch_bounds__(SCAN_BLOCK) void scan1_kernel(
    const int* __restrict__ cnt, int* __restrict__ inc, int* __restrict__ bsum,
    int n) {
  __shared__ int s[SCAN_BLOCK];
  const int tid = threadIdx.x;
  const int i = blockIdx.x * SCAN_BLOCK + tid;
  s[tid] = (i < n) ? cnt[i] : 0;
  __syncthreads();
#pragma unroll
  for (int off = 1; off < SCAN_BLOCK; off <<= 1) {
    int t = (tid >= off) ? s[tid - off] : 0;
    __syncthreads();
    s[tid] += t;
    __syncthreads();
  }
  if (i < n) inc[i] = s[tid];
  if (tid == SCAN_BLOCK - 1) bsum[blockIdx.x] = s[tid];
}

__global__ void scan2_kernel(const int* __restrict__ bsum, int* __restrict__ bpre,
                             int nb) {
  if (threadIdx.x == 0 && blockIdx.x == 0) {
    int run = 0;
    for (int b = 0; b < nb; ++b) {
      bpre[b] = run;
      run += bsum[b];
    }
  }
}

// excl[i] = global exclusive prefix
__global__ __launch_bounds__(SCAN_BLOCK) void scan3_kernel(
    const int* __restrict__ cnt, const int* __restrict__ inc,
    const int* __restrict__ bpre, int* __restrict__ excl, int n) {
  const int i = blockIdx.x * SCAN_BLOCK + threadIdx.x;
  if (i < n) excl[i] = inc[i] + bpre[blockIdx.x] - cnt[i];
}

// Partition: stage tile in LDS sorted by bucket, write contiguous runs
// (avg 42 records = 334 B) -> near-1x write amplification.
__global__ __launch_bounds__(256) void partition_kernel(
    const int* __restrict__ src, const int* __restrict__ dst,
    const float* __restrict__ dvec,
    const float* __restrict__ w_real, const float* __restrict__ w_imag,
    const int* __restrict__ coffs, unsigned long long* __restrict__ records1) {
  __shared__ unsigned long long stage[TILE];   // 32 KB
  __shared__ unsigned short sb[TILE];          // 8 KB
  __shared__ int lhist[128];
  __shared__ int sc[128];
  __shared__ int lbase[K1];
  __shared__ int lcur[K1];
  __shared__ int gbase[K1];
  const int tid = threadIdx.x;
  const int blk = blockIdx.x;
  const int e0 = blk * TILE;
  const int cnt_t = min(TILE, N_EDGES - e0);

  for (int i = tid; i < 128; i += 256) lhist[i] = 0;
  __syncthreads();
  for (int j = tid; j < cnt_t; j += 256)
    atomicAdd(&lhist[dst[e0 + j] >> 10], 1);
  __syncthreads();
  if (tid < 128) sc[tid] = lhist[tid];
  __syncthreads();
  for (int off = 1; off < 128; off <<= 1) {
    int v = (tid < 128 && tid >= off) ? sc[tid - off] : 0;
    __syncthreads();
    if (tid < 128) sc[tid] += v;
    __syncthreads();
  }
  if (tid < K1) {
    const int ex = sc[tid] - lhist[tid];
    lbase[tid] = ex;
    lcur[tid] = ex;
    gbase[tid] = coffs[tid * B1 + blk];
  }
  __syncthreads();

  for (int j = tid; j < cnt_t; j += 256) {
    const int e = e0 + j;
    const int t = dst[e];
    const int s = src[e];
    const int b = t >> 10;
    const float ds = dvec[s];
    const unsigned lo = (unsigned)s | ((unsigned)(t & 1023) << 17);
    const unsigned hi = pack_bf16x2(ds * w_real[e], ds * w_imag[e]);
    const int r = atomicAdd(&lcur[b], 1);
    stage[r] = ((unsigned long long)hi << 32) | lo;
    sb[r] = (unsigned short)b;
  }
  __syncthreads();
  for (int i = tid; i < cnt_t; i += 256) {
    const int b = sb[i];
    records1[gbase[b] + (i - lbase[b])] = stage[i];
  }
}

// One block per bucket: count per-node in LDS, in-block scan -> per-node
// cursors AND global inc[] (replaces global hist + 100K scan). Re-scatter to
// node order: random writes confined to this block's ~131 KB single-owner
// region -> merged in its XCD L2, ~1x amplification.
__global__ __launch_bounds__(1024) void place_kernel(
    const unsigned long long* __restrict__ records1, const int* __restrict__ coffs,
    unsigned long long* __restrict__ records_final, int* __restrict__ inc) {
  const int b = blockIdx.x;
  const int tid = threadIdx.x;
  const int bstart = coffs[b * B1];
  const int bend = (b == K1 - 1) ? N_EDGES : coffs[(b + 1) * B1];
  const int nbase = b << 10;
  const int nn = min(1024, N_NODES - nbase);

  __shared__ int ncnt[1024];
  __shared__ int sc[1024];
  __shared__ int ncur[1024];

  ncnt[tid] = 0;
  __syncthreads();
  for (int i = bstart + tid; i < bend; i += 1024) {
    const unsigned lo = (unsigned)records1[i];
    atomicAdd(&ncnt[(lo >> 17) & 1023], 1);
  }
  __syncthreads();
  const int myc = ncnt[tid];
  sc[tid] = myc;
  __syncthreads();
  for (int off = 1; off < 1024; off <<= 1) {
    int v = (tid >= off) ? sc[tid - off] : 0;
    __syncthreads();
    sc[tid] += v;
    __syncthreads();
  }
  const int base = bstart + sc[tid] - myc;  // exclusive start for node tid
  ncur[tid] = base;
  if (tid < nn) inc[nbase + tid] = base + myc;  // global inclusive prefix
  __syncthreads();
  for (int i = bstart + tid; i < bend; i += 1024) {
    const unsigned long long rec = records1[i];
    const unsigned lo = (unsigned)rec;
    const int pos = atomicAdd(&ncur[(lo >> 17) & 1023], 1);
    records_final[pos] = rec;
  }
}

// One wave per node; unrolled x4 for MLP. Writes Zcat row (128 bf16: zr|zi).
__global__ __launch_bounds__(256) void pull_kernel(
    const uint2* __restrict__ records, const int* __restrict__ inc,
    const float* __restrict__ dvec, const unsigned* __restrict__ hpack,
    unsigned short* __restrict__ zcat) {
  const int lane = threadIdx.x & 63;
  const int n = blockIdx.x * (blockDim.x >> 6) + (threadIdx.x >> 6);
  if (n >= N_NODES) return;

  const int start = (n == 0) ? 0 : inc[n - 1];
  const int end = inc[n];
  const unsigned* __restrict__ hl = hpack + lane;

  float sr = 0.0f, si = 0.0f;
  int p = start;
  for (; p + 4 <= end; p += 4) {
    const uint2 r0 = records[p + 0];
    const uint2 r1 = records[p + 1];
    const uint2 r2 = records[p + 2];
    const uint2 r3 = records[p + 3];
    const unsigned h0 = hl[(size_t)(r0.x & 0x1FFFF) * DIM];
    const unsigned h1 = hl[(size_t)(r1.x & 0x1FFFF) * DIM];
    const unsigned h2 = hl[(size_t)(r2.x & 0x1FFFF) * DIM];
    const unsigned h3 = hl[(size_t)(r3.x & 0x1FFFF) * DIM];
#define ACC(RR, HH)                                                  \
    {                                                                \
      const float er = unpack_lo(RR.y), ei = unpack_hi(RR.y);        \
      const float hr = unpack_lo(HH), hi = unpack_hi(HH);            \
      sr += er * hr - ei * hi;                                       \
      si += ei * hr + er * hi;                                       \
    }
    ACC(r0, h0) ACC(r1, h1) ACC(r2, h2) ACC(r3, h3)
  }
  for (; p < end; ++p) {
    const uint2 r0 = records[p];
    const unsigned h0 = hl[(size_t)(r0.x & 0x1FFFF) * DIM];
    ACC(r0, h0)
  }
#undef ACC

  const float dn = dvec[n];
  zcat[(size_t)n * 128 + lane] = f2bf(dn * sr);
  zcat[(size_t)n * 128 + 64 + lane] = f2bf(dn * si);
}

// MFMA epilogue (unchanged from round 4). zcat aliases the zi half of d_out;
// each wave loads its 16 zcat rows before storing those same rows.
__global__ __launch_bounds__(256) void mfma_epilogue_kernel(
    const unsigned short* zcat, const unsigned short* __restrict__ At,
    const float* __restrict__ cvec, float* zr_out, float* zi_out) {
  const int lane = threadIdx.x & 63;
  const int tile = blockIdx.x * (blockDim.x >> 6) + (threadIdx.x >> 6);
  if (tile >= N_NODES / 16) return;
  const int node0 = tile * 16;
  const int m = lane & 15;
  const int q = lane >> 4;

  bf16x8 a[4];
  const unsigned short* arow = zcat + (size_t)(node0 + m) * 128 + q * 8;
#pragma unroll
  for (int c = 0; c < 4; ++c)
    a[c] = *reinterpret_cast<const bf16x8*>(arow + c * 32);

  f32x4 acc[8];
#pragma unroll
  for (int t = 0; t < 8; ++t) {
    acc[t] = (f32x4){0.f, 0.f, 0.f, 0.f};
    const unsigned short* brow = At + (size_t)(t * 16 + m) * 128 + q * 8;
#pragma unroll
    for (int c = 0; c < 4; ++c) {
      bf16x8 bfrag = *reinterpret_cast<const bf16x8*>(brow + c * 32);
      acc[t] = __builtin_amdgcn_mfma_f32_16x16x32_bf16(a[c], bfrag, acc[t], 0, 0, 0);
    }
  }

#pragma unroll
  for (int t = 0; t < 8; ++t) {
    const int n = t * 16 + m;
    const float bias = cvec[n];
    float* outp = (n < 64) ? zr_out : zi_out;
    const int nn = n & 63;
#pragma unroll
    for (int r = 0; r < 4; ++r) {
      const int node = node0 + q * 4 + r;
      outp[(size_t)node * 64 + nn] = acc[t][r] + bias;
    }
  }
}

extern "C" void kernel_launch(void* const* d_in, const int* in_sizes, int n_in,
                              void* d_out, int out_size, void* d_ws, size_t ws_size,
                              hipStream_t stream) {
  const float* h_real = (const float*)d_in[0];
  const float* h_imag = (const float*)d_in[1];
  const float* dvec   = (const float*)d_in[2];
  const float* w_real = (const float*)d_in[3];
  const float* w_imag = (const float*)d_in[4];
  const int*   src    = (const int*)d_in[5];
  const int*   dst    = (const int*)d_in[6];
  const float* W1     = (const float*)d_in[7];
  const float* b1     = (const float*)d_in[8];
  const float* W2     = (const float*)d_in[9];
  const float* b2     = (const float*)d_in[10];

  char* ws = (char*)d_ws;
  unsigned short* At = (unsigned short*)ws;                          // 32 KB
  float* cvec = (float*)(ws + 128 * 128 * 2);                        // 1 KB
  unsigned long long* records1 = (unsigned long long*)(ws + 33792);  // 12.8 MB
  unsigned* hpack = (unsigned*)(ws + 33792 + (size_t)N_EDGES * 8);   // 25.6 MB
  int* counts  = (int*)(ws + 33792 + (size_t)N_EDGES * 8 + (size_t)N_NODES * DIM * 4);
  int* cts_inc = counts + NCOUNTS;
  int* coffs   = cts_inc + NCOUNTS;
  int* cbsum   = coffs + NCOUNTS;
  int* cbpre   = cbsum + NSB_C;
  int* inc     = cbpre + NSB_C;

  float* zr_out = (float*)d_out;
  float* zi_out = zr_out + (size_t)N_NODES * DIM;
  unsigned long long* records_final = (unsigned long long*)zr_out;  // 12.8 MB
  unsigned short* zcat = (unsigned short*)zi_out;

  precompute_kernel<<<64, 256, 0, stream>>>(W1, b1, W2, b2, At, cvec);
  pack_h_kernel<<<(N_NODES * DIM + 255) / 256, 256, 0, stream>>>(h_real, h_imag,
                                                                 hpack);
  hist_buckets_kernel<<<B1, 256, 0, stream>>>(dst, counts);
  scan1_kernel<<<NSB_C, SCAN_BLOCK, 0, stream>>>(counts, cts_inc, cbsum, NCOUNTS);
  scan2_kernel<<<1, 64, 0, stream>>>(cbsum, cbpre, NSB_C);
  scan3_kernel<<<NSB_C, SCAN_BLOCK, 0, stream>>>(counts, cts_inc, cbpre, coffs,
                                                 NCOUNTS);
  partition_kernel<<<B1, 256, 0, stream>>>(src, dst, dvec, w_real, w_imag, coffs,
                                           records1);
  place_kernel<<<K1, 1024, 0, stream>>>(records1, coffs, records_final, inc);

  const int waves_per_block = 4;
  pull_kernel<<<(N_NODES + waves_per_block - 1) / waves_per_block, 256, 0,
                stream>>>((const uint2*)records_final, inc, dvec, hpack, zcat);

  const int tiles = N_NODES / 16;  // 6250
  mfma_epilogue_kernel<<<(tiles + 3) / 4, 256, 0, stream>>>(zcat, At, cvec,
                                                            zr_out, zi_out);
}

// Round 6
// 292.405 us; speedup vs baseline: 4.2517x; 1.0765x over previous
//
#include <hip/hip_runtime.h>
#include <hip/hip_bf16.h>

#define N_NODES 100000
#define N_EDGES 1600000
#define DIM 64

#define TILE 4096
#define B1 ((N_EDGES + TILE - 1) / TILE)        // 391 partition blocks
#define K1 ((N_NODES + 255) / 256)              // 391 buckets of 256 nodes
#define NCOUNTS (K1 * B1)                       // 152881
#define SCAN_BLOCK 1024
#define NSB ((NCOUNTS + SCAN_BLOCK - 1) / SCAN_BLOCK)  // 150
#define PACKB ((N_NODES * DIM + 255) / 256)     // 25000
#define PLACE_CAP 4736                          // bucket mean 4096, sd 64 -> +10 sigma

typedef __attribute__((ext_vector_type(8))) short bf16x8;
typedef __attribute__((ext_vector_type(4))) float f32x4;

#if defined(__has_builtin)
#if __has_builtin(__builtin_amdgcn_fdot2_f32_bf16)
#define HAVE_DOT2 1
typedef __attribute__((ext_vector_type(2))) __bf16 bf16x2v;
#endif
#endif

// ---------------- ws layout ----------------
// At      : 32 KB bf16 (combined epilogue matrix, transposed)
// cvec    : 1 KB
// records : E * 8 B  (u64 {hi=bf16x2 coef, lo=src | dst_local<<17}); written
//           bucket-grouped by partition, re-sorted to node order IN PLACE by place
// hpack   : N*DIM*4B ({bf16 hr, bf16 hi} interleaved)
// counts  : NCOUNTS ints (raw hist -> in-place global exclusive prefix)
// bsum/bpre : NSB ints; inc : N ints (per-node inclusive prefix)
// total ~39.5 MB

__device__ __forceinline__ unsigned pack_bf16x2(float lo, float hi) {
  unsigned ulo = (unsigned)__hip_bfloat16_raw(__float2bfloat16(lo)).x;
  unsigned uhi = (unsigned)__hip_bfloat16_raw(__float2bfloat16(hi)).x;
  return ulo | (uhi << 16);
}
__device__ __forceinline__ float unpack_lo(unsigned u) {
  return __int_as_float((int)(u << 16));
}
__device__ __forceinline__ float unpack_hi(unsigned u) {
  return __int_as_float((int)(u & 0xFFFF0000u));
}
__device__ __forceinline__ unsigned short f2bf(float x) {
  return __hip_bfloat16_raw(__float2bfloat16(x)).x;
}

// Fused setup: pack_h (blocks 0..PACKB-1), precompute of the combined epilogue
// operator (next 64 blocks), per-(bucket,block) histogram (last B1 blocks).
// Combined operator (round-4 derivation):
// zr = zr_in@W1^T - zi_in@W2^T + (b1-b2)
// zi = zr_in@(W1^T W2^T) + zi_in@(W1^T - W2^T W2^T) + ((b1-b2)@W2^T + b1 + b2)
__global__ __launch_bounds__(256) void setup_fused_kernel(
    const float* __restrict__ h_real, const float* __restrict__ h_imag,
    unsigned* __restrict__ hpack, const float* __restrict__ W1,
    const float* __restrict__ b1, const float* __restrict__ W2,
    const float* __restrict__ b2, unsigned short* __restrict__ At,
    float* __restrict__ cvec, const int* __restrict__ dst,
    int* __restrict__ counts) {
  const int bid = blockIdx.x;
  const int tid = threadIdx.x;
  if (bid < PACKB) {
    const int i = bid * 256 + tid;
    if (i < N_NODES * DIM) hpack[i] = pack_bf16x2(h_real[i], h_imag[i]);
    return;
  }
  if (bid < PACKB + 64) {
    const int idx = (bid - PACKB) * 256 + tid;
    if (idx < 128 * 128) {
      const int n = idx >> 7, k = idx & 127;
      float v;
      if (n < 64) {
        v = (k < 64) ? W1[n * 64 + k] : -W2[n * 64 + (k - 64)];
      } else {
        const int nn = n - 64;
        if (k < 64) {
          float s = 0.0f;
          for (int j = 0; j < 64; ++j) s += W1[j * 64 + k] * W2[nn * 64 + j];
          v = s;
        } else {
          const int kk = k - 64;
          float s = 0.0f;
          for (int j = 0; j < 64; ++j) s += W2[j * 64 + kk] * W2[nn * 64 + j];
          v = W1[nn * 64 + kk] - s;
        }
      }
      At[n * 128 + k] = f2bf(v);
    }
    if (idx < 128) {
      if (idx < 64) {
        cvec[idx] = b1[idx] - b2[idx];
      } else {
        const int nn = idx - 64;
        float s = 0.0f;
        for (int j = 0; j < 64; ++j) s += (b1[j] - b2[j]) * W2[nn * 64 + j];
        cvec[idx] = s + b1[nn] + b2[nn];
      }
    }
    return;
  }
  // histogram role
  __shared__ int lh[K1];
  const int hb = bid - PACKB - 64;
  for (int i = tid; i < K1; i += 256) lh[i] = 0;
  __syncthreads();
  const int e0 = hb * TILE;
  const int e1 = min(e0 + TILE, N_EDGES);
  for (int e = e0 + tid; e < e1; e += 256) atomicAdd(&lh[dst[e] >> 8], 1);
  __syncthreads();
  for (int b = tid; b < K1; b += 256) counts[b * B1 + hb] = lh[b];
}

// In-place: counts -> local exclusive prefix; bsum[blk] = block total.
__global__ __launch_bounds__(SCAN_BLOCK) void scan1_kernel(
    int* __restrict__ cnt, int* __restrict__ bsum) {
  __shared__ int s[SCAN_BLOCK];
  const int tid = threadIdx.x;
  const int i = blockIdx.x * SCAN_BLOCK + tid;
  const int v = (i < NCOUNTS) ? cnt[i] : 0;
  s[tid] = v;
  __syncthreads();
#pragma unroll
  for (int off = 1; off < SCAN_BLOCK; off <<= 1) {
    int t = (tid >= off) ? s[tid - off] : 0;
    __syncthreads();
    s[tid] += t;
    __syncthreads();
  }
  if (i < NCOUNTS) cnt[i] = s[tid] - v;  // exclusive local
  if (tid == SCAN_BLOCK - 1) bsum[blockIdx.x] = s[tid];
}

__global__ void scan2_kernel(const int* __restrict__ bsum, int* __restrict__ bpre) {
  if (threadIdx.x == 0 && blockIdx.x == 0) {
    int run = 0;
    for (int b = 0; b < NSB; ++b) {
      bpre[b] = run;
      run += bsum[b];
    }
  }
}

// counts += bpre[blk] -> global exclusive prefix (coffs)
__global__ __launch_bounds__(SCAN_BLOCK) void scan3_kernel(
    int* __restrict__ cnt, const int* __restrict__ bpre) {
  const int i = blockIdx.x * SCAN_BLOCK + threadIdx.x;
  if (i < NCOUNTS) cnt[i] += bpre[blockIdx.x];
}

// Partition: stage tile in LDS sorted by bucket, write contiguous runs.
__global__ __launch_bounds__(512) void partition_kernel(
    const int* __restrict__ src, const int* __restrict__ dst,
    const float* __restrict__ dvec,
    const float* __restrict__ w_real, const float* __restrict__ w_imag,
    const int* __restrict__ coffs, unsigned long long* __restrict__ records) {
  __shared__ unsigned long long stage[TILE];  // 32 KB
  __shared__ unsigned short sb[TILE];         // 8 KB
  __shared__ int lhist[512];
  __shared__ int lbase[K1];
  __shared__ int lcur[K1];
  __shared__ int gbase[K1];
  const int tid = threadIdx.x;
  const int blk = blockIdx.x;
  const int e0 = blk * TILE;
  const int cnt_t = min(TILE, N_EDGES - e0);

  lhist[tid] = 0;
  __syncthreads();
  for (int j = tid; j < cnt_t; j += 512) atomicAdd(&lhist[dst[e0 + j] >> 8], 1);
  __syncthreads();
  const int myc = lhist[tid];
  __syncthreads();
#pragma unroll
  for (int off = 1; off < 512; off <<= 1) {
    int v = (tid >= off) ? lhist[tid - off] : 0;
    __syncthreads();
    lhist[tid] += v;
    __syncthreads();
  }
  if (tid < K1) {
    const int ex = lhist[tid] - myc;
    lbase[tid] = ex;
    lcur[tid] = ex;
    gbase[tid] = coffs[tid * B1 + blk];
  }
  __syncthreads();

  for (int j = tid; j < cnt_t; j += 512) {
    const int e = e0 + j;
    const int t = dst[e];
    const int s = src[e];
    const int b = t >> 8;
    const float ds = dvec[s];
    const unsigned lo = (unsigned)s | ((unsigned)(t & 255) << 17);
    const unsigned hi = pack_bf16x2(ds * w_real[e], ds * w_imag[e]);
    const int r = atomicAdd(&lcur[b], 1);
    stage[r] = ((unsigned long long)hi << 32) | lo;
    sb[r] = (unsigned short)b;
  }
  __syncthreads();
  for (int i = tid; i < cnt_t; i += 512) {
    const int b = sb[i];
    records[gbase[b] + (i - lbase[b])] = stage[i];
  }
}

// One block per 256-node bucket: stage region in LDS, per-node count+scan,
// re-scatter IN PLACE to node order. Also writes the global per-node prefix.
__global__ __launch_bounds__(256) void place_kernel(
    unsigned long long* __restrict__ records, const int* __restrict__ coffs,
    int* __restrict__ inc) {
  const int b = blockIdx.x;
  const int tid = threadIdx.x;
  const int bstart = coffs[b * B1];
  const int bend = (b == K1 - 1) ? N_EDGES : coffs[(b + 1) * B1];
  const int cnt = min(bend - bstart, PLACE_CAP);
  const int nbase = b << 8;
  const int nn = min(256, N_NODES - nbase);

  __shared__ unsigned long long stage[PLACE_CAP];  // 37 KB
  __shared__ int ncnt[256];
  __shared__ int ncur[256];

  ncnt[tid] = 0;
  __syncthreads();
  for (int i = tid; i < cnt; i += 256) {
    const unsigned long long rec = records[bstart + i];
    stage[i] = rec;
    atomicAdd(&ncnt[((unsigned)rec >> 17) & 255], 1);
  }
  __syncthreads();
  const int myc = ncnt[tid];
  __syncthreads();
#pragma unroll
  for (int off = 1; off < 256; off <<= 1) {
    int v = (tid >= off) ? ncnt[tid - off] : 0;
    __syncthreads();
    ncnt[tid] += v;
    __syncthreads();
  }
  const int base = bstart + ncnt[tid] - myc;
  ncur[tid] = base;
  if (tid < nn) inc[nbase + tid] = base + myc;
  __syncthreads();
  for (int i = tid; i < cnt; i += 256) {
    const unsigned long long rec = stage[i];
    const int pos = atomicAdd(&ncur[((unsigned)rec >> 17) & 255], 1);
    records[pos] = rec;
  }
}

// Fused pull + MFMA epilogue. 16 waves = 16 nodes per block; each wave
// accumulates its node's complex aggregate via bf16 dot2, stages the bf16
// zcat row in LDS; waves 0..7 then run the 8 MFMA column-tiles to d_out.
__global__ __launch_bounds__(1024) void pull_fused_kernel(
    const uint2* __restrict__ records, const int* __restrict__ inc,
    const float* __restrict__ dvec, const unsigned* __restrict__ hpack,
    const unsigned short* __restrict__ At, const float* __restrict__ cvec,
    float* __restrict__ zr_out, float* __restrict__ zi_out) {
  __shared__ unsigned short zs[16][136];  // row pad: 272 B -> bank rotate by 4
  const int lane = threadIdx.x & 63;
  const int wave = threadIdx.x >> 6;
  const int node0 = blockIdx.x * 16;  // grid = N/16 exact
  const int n = node0 + wave;

  const int start = (n == 0) ? 0 : inc[n - 1];
  const int end = inc[n];
  const unsigned* __restrict__ hl = hpack + lane;

  float sr = 0.0f, si = 0.0f;
  int p = start;
#if HAVE_DOT2
#define ACC(RR, HH)                                                     \
  {                                                                     \
    const unsigned wneg = RR.y ^ 0x80000000u;        /* (er,-ei) */     \
    const unsigned wswp = (RR.y >> 16) | (RR.y << 16); /* (ei, er) */   \
    const bf16x2v hv = __builtin_bit_cast(bf16x2v, HH);                 \
    sr = __builtin_amdgcn_fdot2_f32_bf16(__builtin_bit_cast(bf16x2v, wneg), \
                                         hv, sr, false);                \
    si = __builtin_amdgcn_fdot2_f32_bf16(__builtin_bit_cast(bf16x2v, wswp), \
                                         hv, si, false);                \
  }
#else
#define ACC(RR, HH)                                                     \
  {                                                                     \
    const float er = unpack_lo(RR.y), ei = unpack_hi(RR.y);             \
    const float hr = unpack_lo(HH), hi = unpack_hi(HH);                 \
    sr += er * hr - ei * hi;                                            \
    si += ei * hr + er * hi;                                            \
  }
#endif
  for (; p + 4 <= end; p += 4) {
    const uint2 r0 = records[p + 0];
    const uint2 r1 = records[p + 1];
    const uint2 r2 = records[p + 2];
    const uint2 r3 = records[p + 3];
    const unsigned h0 = hl[(size_t)(r0.x & 0x1FFFF) * DIM];
    const unsigned h1 = hl[(size_t)(r1.x & 0x1FFFF) * DIM];
    const unsigned h2 = hl[(size_t)(r2.x & 0x1FFFF) * DIM];
    const unsigned h3 = hl[(size_t)(r3.x & 0x1FFFF) * DIM];
    ACC(r0, h0) ACC(r1, h1) ACC(r2, h2) ACC(r3, h3)
  }
  for (; p < end; ++p) {
    const uint2 r0 = records[p];
    const unsigned h0 = hl[(size_t)(r0.x & 0x1FFFF) * DIM];
    ACC(r0, h0)
  }
#undef ACC

  const float dn = dvec[n];
  zs[wave][lane] = f2bf(dn * sr);
  zs[wave][64 + lane] = f2bf(dn * si);
  __syncthreads();

  // Epilogue: Out[node][f] = sum_k Zcat[node][k]*A_comb[k][f] + cvec[f].
  // Wave t (t<8) computes feature tile [t*16, t*16+16) for all 16 nodes.
  if (wave < 8) {
    const int t = wave;
    const int m = lane & 15;
    const int q = lane >> 4;

    bf16x8 a[4];
#pragma unroll
    for (int c = 0; c < 4; ++c)
      a[c] = *reinterpret_cast<const bf16x8*>(&zs[m][c * 32 + q * 8]);

    f32x4 acc = (f32x4){0.f, 0.f, 0.f, 0.f};
    const unsigned short* brow = At + (size_t)(t * 16 + m) * 128 + q * 8;
#pragma unroll
    for (int c = 0; c < 4; ++c) {
      bf16x8 bfrag = *reinterpret_cast<const bf16x8*>(brow + c * 32);
      acc = __builtin_amdgcn_mfma_f32_16x16x32_bf16(a[c], bfrag, acc, 0, 0, 0);
    }

    const int nf = t * 16 + m;
    const float bias = cvec[nf];
    float* outp = (nf < 64) ? zr_out : zi_out;
    const int nn = nf & 63;
#pragma unroll
    for (int r = 0; r < 4; ++r) {
      const int node = node0 + q * 4 + r;
      outp[(size_t)node * 64 + nn] = acc[r] + bias;
    }
  }
}

extern "C" void kernel_launch(void* const* d_in, const int* in_sizes, int n_in,
                              void* d_out, int out_size, void* d_ws, size_t ws_size,
                              hipStream_t stream) {
  const float* h_real = (const float*)d_in[0];
  const float* h_imag = (const float*)d_in[1];
  const float* dvec   = (const float*)d_in[2];
  const float* w_real = (const float*)d_in[3];
  const float* w_imag = (const float*)d_in[4];
  const int*   src    = (const int*)d_in[5];
  const int*   dst    = (const int*)d_in[6];
  const float* W1     = (const float*)d_in[7];
  const float* b1     = (const float*)d_in[8];
  const float* W2     = (const float*)d_in[9];
  const float* b2     = (const float*)d_in[10];

  char* ws = (char*)d_ws;
  unsigned short* At = (unsigned short*)ws;                          // 32 KB
  float* cvec = (float*)(ws + 128 * 128 * 2);                        // 1 KB
  unsigned long long* records = (unsigned long long*)(ws + 33792);   // 12.8 MB
  unsigned* hpack = (unsigned*)(ws + 33792 + (size_t)N_EDGES * 8);   // 25.6 MB
  int* counts = (int*)(ws + 33792 + (size_t)N_EDGES * 8 + (size_t)N_NODES * DIM * 4);
  int* bsum = counts + NCOUNTS;
  int* bpre = bsum + NSB;
  int* inc  = bpre + NSB;

  float* zr_out = (float*)d_out;
  float* zi_out = zr_out + (size_t)N_NODES * DIM;

  setup_fused_kernel<<<PACKB + 64 + B1, 256, 0, stream>>>(
      h_real, h_imag, (unsigned*)hpack, W1, b1, W2, b2, At, cvec, dst, counts);
  scan1_kernel<<<NSB, SCAN_BLOCK, 0, stream>>>(counts, bsum);
  scan2_kernel<<<1, 64, 0, stream>>>(bsum, bpre);
  scan3_kernel<<<NSB, SCAN_BLOCK, 0, stream>>>(counts, bpre);
  partition_kernel<<<B1, 512, 0, stream>>>(src, dst, dvec, w_real, w_imag,
                                           counts, records);
  place_kernel<<<K1, 256, 0, stream>>>(records, counts, inc);
  pull_fused_kernel<<<N_NODES / 16, 1024, 0, stream>>>(
      (const uint2*)records, inc, dvec, hpack, At, cvec, zr_out, zi_out);
}